// Round 4
// baseline (271.489 us; speedup 1.0000x reference)
//
#include <hip/hip_runtime.h>

// Multi-scale deformable attention, fp32 — XCD-locality version.
// Block = (b, h, q-chunk of 8): one (b,h) value slice is 2.78 MB < 4 MiB L2/XCD.
// blockIdx layout: x = blockIdx&7 (XCD slot = h), t = blockIdx>>3, b = t/113,
// qc = t%113  -> each XCD processes its h-slice for b=0..7 SEQUENTIALLY,
// so all ~2.6 draws of each value line hit the same XCD's L2.
// thread = (q-sub(3b hi) | lvl(2b) | cg(3b)); shfl_xor 8/16 reduces over lvl.
// shapes: bs=8, nq=900, nh=8, d=32, nl=4, npt=4; value: (bs, 22223, nh, d)

#define BS 8
#define NQ 900
#define NH 8
#define NL 4
#define NPT 4
#define NUM_KEYS 22223
#define QCHUNKS 113   // ceil(900/8)

__global__ __launch_bounds__(256) void msda_kernel(
    const float* __restrict__ value,
    const float* __restrict__ loc,
    const float* __restrict__ aw,
    float* __restrict__ out)
{
    // block -> (b, h, qc) with XCD affinity on h
    const int x  = blockIdx.x & 7;      // XCD slot == h
    const int t  = blockIdx.x >> 3;     // 0..903
    const int b  = t / QCHUNKS;         // 0..7
    const int qc = t - b * QCHUNKS;     // 0..112
    const int h  = x;

    const int cg  = threadIdx.x & 7;         // channel group (4 floats)
    const int lvl = (threadIdx.x >> 3) & 3;  // level, lane bits 3-4
    const int qs  = threadIdx.x >> 5;        // 0..7
    const int q   = qc * 8 + qs;
    if (q >= NQ) return;  // shfl partners (xor 8/16: same qs) exit together

    // per-thread level constants
    const bool l01 = lvl < 2;
    const int H  = l01 ? (lvl == 0 ? 100 : 50)  : (lvl == 2 ? 25 : 13);
    const int W  = l01 ? (lvl == 0 ? 167 : 84)  : (lvl == 2 ? 42 : 21);
    const int St = l01 ? (lvl == 0 ? 0 : 16700) : (lvl == 2 ? 20900 : 21950);

    const float4* __restrict__ v4 = (const float4*)value;
    // value float4 index: ((b*NUM_KEYS + key)*NH + h)*8 + cg — fits 32 bits
    const unsigned vbase = (unsigned)b * (NUM_KEYS * NH * 8) + h * 8 + cg
                         + (unsigned)St * (NH * 8);
    const unsigned rowstride = (unsigned)W * (NH * 8);

    // loc: (b,q,h,lvl,npt,2) -> 2 float4 per (b,q,h,lvl); aw -> 1 float4
    const int lidx = ((b * NQ + q) * NH + h) * NL + lvl;
    const float4* __restrict__ loc4 = (const float4*)loc;
    const float4* __restrict__ aw4  = (const float4*)aw;
    const float4 xy01 = loc4[lidx * 2];
    const float4 xy23 = loc4[lidx * 2 + 1];
    const float4 wv   = aw4[lidx];

    const float xs[NPT] = {xy01.x, xy01.z, xy23.x, xy23.z};
    const float ys[NPT] = {xy01.y, xy01.w, xy23.y, xy23.w};
    const float ws[NPT] = {wv.x, wv.y, wv.z, wv.w};

    float4 acc = {0.f, 0.f, 0.f, 0.f};

    #pragma unroll
    for (int p = 0; p < NPT; ++p) {
        const float xf = xs[p] * (float)W - 0.5f;
        const float yf = ys[p] * (float)H - 0.5f;
        const float w  = ws[p];
        const float fx0 = floorf(xf);
        const float fy0 = floorf(yf);
        const int x0 = (int)fx0;
        const int y0 = (int)fy0;
        float wx1 = xf - fx0, wy1 = yf - fy0;
        float wx0 = 1.f - wx1, wy0 = 1.f - wy1;

        // zero out-of-bounds corner weights instead of branching
        wx0 = (x0 >= 0 && x0 <= W - 1)         ? wx0 : 0.f;
        wx1 = (x0 + 1 >= 0 && x0 + 1 <= W - 1) ? wx1 : 0.f;
        wy0 = (y0 >= 0 && y0 <= H - 1)         ? wy0 : 0.f;
        wy1 = (y0 + 1 >= 0 && y0 + 1 <= H - 1) ? wy1 : 0.f;

        const int x0c = min(max(x0, 0), W - 1);
        const int x1c = min(max(x0 + 1, 0), W - 1);
        const int y0c = min(max(y0, 0), H - 1);
        const int y1c = min(max(y0 + 1, 0), H - 1);

        const unsigned r0 = vbase + (unsigned)y0c * rowstride;
        const unsigned r1 = vbase + (unsigned)y1c * rowstride;

        const float4 v00 = v4[r0 + (unsigned)x0c * (NH * 8)];
        const float4 v01 = v4[r0 + (unsigned)x1c * (NH * 8)];
        const float4 v10 = v4[r1 + (unsigned)x0c * (NH * 8)];
        const float4 v11 = v4[r1 + (unsigned)x1c * (NH * 8)];

        const float s00 = w * wx0 * wy0;
        const float s01 = w * wx1 * wy0;
        const float s10 = w * wx0 * wy1;
        const float s11 = w * wx1 * wy1;

        acc.x = fmaf(s00, v00.x, acc.x); acc.y = fmaf(s00, v00.y, acc.y);
        acc.z = fmaf(s00, v00.z, acc.z); acc.w = fmaf(s00, v00.w, acc.w);
        acc.x = fmaf(s01, v01.x, acc.x); acc.y = fmaf(s01, v01.y, acc.y);
        acc.z = fmaf(s01, v01.z, acc.z); acc.w = fmaf(s01, v01.w, acc.w);
        acc.x = fmaf(s10, v10.x, acc.x); acc.y = fmaf(s10, v10.y, acc.y);
        acc.z = fmaf(s10, v10.z, acc.z); acc.w = fmaf(s10, v10.w, acc.w);
        acc.x = fmaf(s11, v11.x, acc.x); acc.y = fmaf(s11, v11.y, acc.y);
        acc.z = fmaf(s11, v11.z, acc.z); acc.w = fmaf(s11, v11.w, acc.w);
    }

    // reduce across the 4 level-threads (lane bits 3 and 4)
    acc.x += __shfl_xor(acc.x, 8);  acc.y += __shfl_xor(acc.y, 8);
    acc.z += __shfl_xor(acc.z, 8);  acc.w += __shfl_xor(acc.w, 8);
    acc.x += __shfl_xor(acc.x, 16); acc.y += __shfl_xor(acc.y, 16);
    acc.z += __shfl_xor(acc.z, 16); acc.w += __shfl_xor(acc.w, 16);

    if (lvl == 0) {
        float4* __restrict__ out4 = (float4*)out;
        out4[((b * NQ + q) * NH + h) * 8 + cg] = acc;
    }
}

extern "C" void kernel_launch(void* const* d_in, const int* in_sizes, int n_in,
                              void* d_out, int out_size, void* d_ws, size_t ws_size,
                              hipStream_t stream) {
    const float* value = (const float*)d_in[0];
    const float* loc   = (const float*)d_in[1];
    const float* aw    = (const float*)d_in[2];
    float* outp = (float*)d_out;

    const int grid = 8 * BS * QCHUNKS;   // 7232 blocks: (xcd/h slot) x (b) x (qc)
    msda_kernel<<<grid, 256, 0, stream>>>(value, loc, aw, outp);
}